// Round 12
// baseline (147.037 us; speedup 1.0000x reference)
//
#include <hip/hip_runtime.h>

// B=65536, Q=128, S=8, U=32
// out[b,q] = b2[q] + sum_u elu(b1[q,u] + sum_s x[b,q,s]*W1[q,s,u]) * W2[q,u]
//
// R12: contiguous-x restructure (H1: strided 512B reads cap memory at ~2.3TB/s).
//  - ROWS=32, q-hyperchunks of 64: each block reads a CONTIGUOUS 64KB per
//    chunk (2KB per row half, rows adjacent), 128KB total.
//  - 512 threads (8 waves), 2 blocks/CU (69.6KB LDS), wave handles 8 q/chunk.
//  - buffers use R9's measured-conflict-free [sub16q][row*272B] layout.
//  - chunk-1 loads reg-prefetched under chunk-0 compute; 2 barriers total.
//  - per-qi compute = R9 verified path: 1 MFMA (K=8 pad, zero-page upper
//    lanes), 5-op ELU (prep: b1+1, b2-sum(W2)), shfl_xor(32) u-combine.
#define Q    128
#define S    8
#define U    32
#define ROWS 32
#define QCH  64
#define NCH  2
#define NT   512
#define RSTRIDE 272
#define SUBSZ (ROWS * RSTRIDE)     // 8704 B (16 q)
#define XBUF  (4 * SUBSZ)          // 34816 B per chunk buffer
#define ZOFF  (2 * XBUF)           // zero-page offset

typedef __attribute__((ext_vector_type(8)))  __bf16 bf16x8;
typedef __attribute__((ext_vector_type(16))) float  f32x16;
typedef __attribute__((ext_vector_type(2)))  float  f32x2;

__device__ inline unsigned short f2bf(float f) {   // RTN f32->bf16 (prep only)
    unsigned int u = __float_as_uint(f);
    u += 0x7FFF + ((u >> 16) & 1);
    return (unsigned short)(u >> 16);
}

__device__ inline unsigned int cvt_pk_bf16(float lo, float hi) {
    unsigned int r;
    asm("v_cvt_pk_bf16_f32 %0, %1, %2" : "=v"(r) : "v"(lo), "v"(hi));
    return r;
}

// ---- prep: W1T[q][u][s] bf16 ; b1F=(b1+1), w2F in C-reg order ; b2F=b2-sum(W2)
__global__ void prep_kernel(const float* __restrict__ W1, const float* __restrict__ b1,
                            const float* __restrict__ W2, const float* __restrict__ b2,
                            unsigned short* __restrict__ W1T,
                            float* __restrict__ b1F, float* __restrict__ w2F,
                            float* __restrict__ b2F)
{
    const int q = blockIdx.x, t = threadIdx.x;     // 128 blocks x 256 threads
    const int u = t & 31, s = t >> 5;
    W1T[(q * 32 + u) * 8 + s] = f2bf(W1[(q * 8 + s) * 32 + u]);
    if (t < 32) {
        int reg = t & 15, hh = t >> 4;
        int uu  = (reg & 3) + 8 * (reg >> 2) + 4 * hh;   // verified C/D row map
        b1F[(q * 2 + hh) * 16 + reg] = b1[q * 32 + uu] + 1.0f;
        w2F[(q * 2 + hh) * 16 + reg] = W2[q * 32 + uu];
    }
    if (t == 0) {
        float sw = 0.f;
        for (int uu = 0; uu < 32; ++uu) sw += W2[q * 32 + uu];
        b2F[q] = b2[q] - sw;
    }
}

__global__ __launch_bounds__(NT)
__attribute__((amdgpu_waves_per_eu(4, 4)))   // budget 128 VGPR; LDS caps 2 blk/CU
void divenc_mfma(const float* __restrict__ x,
                 const unsigned short* __restrict__ W1T,
                 const float* __restrict__ b1F,
                 const float* __restrict__ w2F,
                 const float* __restrict__ b2F,
                 float* __restrict__ out, int B)
{
    __shared__ __align__(16) unsigned char xs[2 * XBUF + 16];  // 69.65 KB

    const int t     = threadIdx.x;
    const int lane  = t & 63;
    const int wv    = __builtin_amdgcn_readfirstlane(t >> 6);  // 0..7
    const int rbase = blockIdx.x * ROWS;
    const int rmax  = B - 1;
    const int bl    = lane & 31;             // b-row (col of D) / u (A row)
    const int h     = lane >> 5;
    const bool lo   = (lane < 32);

    if (t == 0) *(uint4*)(xs + ZOFF) = uint4{0, 0, 0, 0};   // zero page

    const f32x2 l2e2  = 1.44269504088896f;
    const f32x2 nl2e2 = -1.44269504088896f;
    const f32x2 zero2 = 0.0f;

    float4 xr0, xr1, xr2, xr3, xr4, xr5, xr6, xr7;   // prefetch regs (32 VGPR)

// contiguous load: idx in [0,4096) f4 units; row = idx>>7 (128 f4 per 2KB
// half-row), f = idx&127 -> q_in_chunk = f>>1, s-half = f&1
#define LDK(K, CH) { int idx_ = t + K * NT; int row_ = idx_ >> 7, f_ = idx_ & 127;   \
        int r_ = rbase + row_; if (r_ > rmax) r_ = rmax;                             \
        xr##K = ((const float4*)x)[(size_t)r_ * (Q * S / 4) + (CH) * (QCH * S / 4) + f_]; }
#define WRK(K, BASE) { int idx_ = t + K * NT; int row_ = idx_ >> 7, f_ = idx_ & 127; \
        uint2 w_;                                                                    \
        w_.x = cvt_pk_bf16(xr##K.x, xr##K.y); w_.y = cvt_pk_bf16(xr##K.z, xr##K.w);  \
        *(uint2*)(xs + (BASE) + (f_ >> 5) * SUBSZ + row_ * RSTRIDE                   \
                  + ((f_ >> 1) & 15) * 16 + (f_ & 1) * 8) = w_; }

    // ---- prologue: chunk 0 -> buf 0 ----
    LDK(0, 0) LDK(1, 0) LDK(2, 0) LDK(3, 0) LDK(4, 0) LDK(5, 0) LDK(6, 0) LDK(7, 0)
    WRK(0, 0) WRK(1, 0) WRK(2, 0) WRK(3, 0) WRK(4, 0) WRK(5, 0) WRK(6, 0) WRK(7, 0)

    #pragma unroll 1
    for (int ch = 0; ch < NCH; ++ch) {
        const int rbuf = ch * XBUF;
        __syncthreads();                      // buf[ch] ready

        if (ch == 0) {                        // prefetch chunk 1 under compute
            LDK(0, 1) LDK(1, 1) LDK(2, 1) LDK(3, 1)
            LDK(4, 1) LDK(5, 1) LDK(6, 1) LDK(7, 1)
        }

        // ---- compute: wave wv handles q = ch*64 + wv*8 + qi ----
        #pragma unroll 1
        for (int qi = 0; qi < 8; ++qi) {
            const int qr = wv * 8 + qi;       // 0..63, uniform per wave
            const int q  = ch * QCH + qr;

            const int xoff = rbuf + (qr >> 4) * SUBSZ + bl * RSTRIDE + (qr & 15) * 16;
            uint4 bx = *(const uint4*)(xs + (lo ? xoff : ZOFF));

            uint4 ax = *(const uint4*)(W1T + ((size_t)q * 32 + bl) * 8);
            f32x16 cin = *(const f32x16*)(b1F + ((size_t)q * 2 + h) * 16);

            f32x16 cc = __builtin_amdgcn_mfma_f32_32x32x16_bf16(
                __builtin_bit_cast(bf16x8, ax), __builtin_bit_cast(bf16x8, bx),
                cin, 0, 0, 0);

            f32x16 wr = *(const f32x16*)(w2F + ((size_t)q * 2 + h) * 16);
            const float b2v = b2F[q];

            // ---- 5-op ELU+1: r = max(v', exp2(min(v'*log2e - log2e, 0))) ----
#define EL2(J, ACC) {                                                                \
        f32x2 v_; v_.x = cc[2*(J)]; v_.y = cc[2*(J)+1];                              \
        f32x2 w2v; w2v.x = wr[2*(J)]; w2v.y = wr[2*(J)+1];                           \
        f32x2 f_ = __builtin_elementwise_fma(v_, l2e2, nl2e2);                       \
        f_ = __builtin_elementwise_min(f_, zero2);                                   \
        f32x2 e_; e_.x = __builtin_amdgcn_exp2f(f_.x);                               \
        e_.y = __builtin_amdgcn_exp2f(f_.y);                                         \
        f32x2 r_ = __builtin_elementwise_max(v_, e_);                                \
        ACC = __builtin_elementwise_fma(r_, w2v, ACC); }

            f32x2 acc = 0.0f;
            EL2(0, acc) EL2(1, acc) EL2(2, acc) EL2(3, acc)
            EL2(4, acc) EL2(5, acc) EL2(6, acc) EL2(7, acc)
#undef EL2

            float a0 = acc.x + acc.y;
            a0 += __shfl_xor(a0, 32);         // combine u-halves

            const int r0 = rbase + bl;
            if (lo && r0 < B) out[(size_t)r0 * Q + q] = a0 + b2v;
        }

        if (ch == 0) {                        // write prefetched chunk 1
            WRK(0, XBUF) WRK(1, XBUF) WRK(2, XBUF) WRK(3, XBUF)
            WRK(4, XBUF) WRK(5, XBUF) WRK(6, XBUF) WRK(7, XBUF)
        }
    }
#undef LDK
#undef WRK
}

extern "C" void kernel_launch(void* const* d_in, const int* in_sizes, int n_in,
                              void* d_out, int out_size, void* d_ws, size_t ws_size,
                              hipStream_t stream) {
    const float* x  = (const float*)d_in[0];
    const float* W1 = (const float*)d_in[1];
    const float* b1 = (const float*)d_in[2];
    const float* W2 = (const float*)d_in[3];
    const float* b2 = (const float*)d_in[4];
    float* out = (float*)d_out;

    unsigned short* W1T = (unsigned short*)d_ws;                 // 64 KB
    float*          b1F = (float*)((char*)d_ws + 65536);         // 16 KB
    float*          w2F = (float*)((char*)d_ws + 81920);         // 16 KB
    float*          b2F = (float*)((char*)d_ws + 98304);         // 512 B

    const int B = in_sizes[0] / (Q * S);

    hipLaunchKernelGGL(prep_kernel, dim3(Q), dim3(256), 0, stream,
                       W1, b1, W2, b2, W1T, b1F, w2F, b2F);
    hipLaunchKernelGGL(divenc_mfma, dim3((B + ROWS - 1) / ROWS), dim3(NT), 0, stream,
                       x, W1T, b1F, w2F, b2F, out, B);
}